// Round 10
// baseline (3380.606 us; speedup 1.0000x reference)
//
#include <hip/hip_runtime.h>
#include <math.h>

#define BB 128
#define NN 2048
#define CMID 64
#define HH 128
#define G4 512
#define NCLS 40
#define CH 32
#define NCH (NN / CH)
#define EPSV 1e-5f
#define HPAD 36

typedef float f32x2 __attribute__((ext_vector_type(2)));

__device__ __forceinline__ float fsigmoid(float x) {
    return 1.0f / (1.0f + __expf(-x));
}
__device__ __forceinline__ float ftanh2(float x) {
    return 2.0f / (1.0f + __expf(-2.0f * x)) - 1.0f;
}
// AGPR park (R9-proven mechanics).  aread is NON-volatile but carries a
// loop-variant dep operand so it can be scheduled freely within an iteration
// yet never hoisted out of the loop (which would re-create VGPR pressure).
__device__ __forceinline__ void awrite(float& a, float v) {
    asm volatile("v_accvgpr_write_b32 %0, %1" : "=a"(a) : "v"(v));
}
__device__ __forceinline__ float aread(const float& a, int dep) {
    float v;
    asm("v_accvgpr_read_b32 %0, %1" : "=v"(v) : "a"(a), "v"(dep));
    return v;
}
// Packed fp32 FMA: 2 MACs/instr (VOP3P, gfx90a+).
__device__ __forceinline__ void pkfma(f32x2& d, f32x2 a, f32x2 b) {
    asm("v_pk_fma_f32 %0, %1, %2, %0" : "+v"(d) : "v"(a), "v"(b));
}

// 512 threads, 1 block/batch.  Per 32-step chunk: phase-0 conv+BN+ReLU->hcT;
// phase-1 xg = bias + W_ih*hc -> LDS (pk_fma, broadcast reads); phase-2 serial
// recurrence: thread=(unit j=t>>2, slice s=t&3, 32 h-dims).  W_hh gates i,f
// resident in VGPRs (64 floats), gates g,o parked in AGPRs (64 floats, read
// per use).  One barrier per step; xg carries both biases.
__global__ __attribute__((amdgpu_flat_work_group_size(512, 512),
                          amdgpu_waves_per_eu(2, 2)))
void lstm_seq_kernel(const float* __restrict__ x,
                     const float* __restrict__ conv_w, const float* __restrict__ conv_b,
                     const float* __restrict__ gamma,  const float* __restrict__ beta,
                     const float* __restrict__ rmean,  const float* __restrict__ rvar,
                     const float* __restrict__ W_ih,   const float* __restrict__ W_hh,
                     const float* __restrict__ b_ih,   const float* __restrict__ b_hh,
                     const float* __restrict__ W_out,  const float* __restrict__ b_out,
                     float* __restrict__ out)
{
    __shared__ float xg_s[CH][4][HH];    // 64 KB: gate pre-activations
    __shared__ float hcT[CMID][HPAD];    // 9 KB:  hc transposed, padded rows
    __shared__ float h_p[2][4][HPAD];    // hidden, slice-padded + dbuf
    __shared__ float cf_s[4][CMID];      // folded conv+BN coeffs
    __shared__ float bias_s[G4];         // b_ih + b_hh

    const int t = threadIdx.x;
    const int b = blockIdx.x;
    const int j = t >> 2;    // unit 0..127
    const int s = t & 3;     // h-slice 0..3 (32 dims)

    if (t < CMID) {
        float inv = gamma[t] * rsqrtf(rvar[t] + EPSV);
        cf_s[0][t] = conv_w[t * 3 + 0] * inv;
        cf_s[1][t] = conv_w[t * 3 + 1] * inv;
        cf_s[2][t] = conv_w[t * 3 + 2] * inv;
        cf_s[3][t] = (conv_b[t] - rmean[t]) * inv + beta[t];
    }
    bias_s[t] = b_ih[t] + b_hh[t];
    if (t < 2 * 4 * HPAD) ((float*)h_p)[t] = 0.0f;

    // ---- W_hh residency: i,f gates -> VGPR pairs; g,o gates -> AGPRs ----
    f32x2 wif[2][16];
    #pragma unroll
    for (int q = 0; q < 2; ++q) {
        const float* p = W_hh + (size_t)(q * HH + j) * HH + s * 32;
        #pragma unroll
        for (int i = 0; i < 8; ++i) {
            float4 w4 = *(const float4*)(p + 4 * i);
            wif[q][2 * i].x     = w4.x; wif[q][2 * i].y     = w4.y;
            wif[q][2 * i + 1].x = w4.z; wif[q][2 * i + 1].y = w4.w;
        }
    }
    float wag[32], wao[32];
    #pragma unroll
    for (int i = 0; i < 8; ++i) {
        float4 wg = *(const float4*)(W_hh + (size_t)(2 * HH + j) * HH + s * 32 + 4 * i);
        float4 wo = *(const float4*)(W_hh + (size_t)(3 * HH + j) * HH + s * 32 + 4 * i);
        awrite(wag[4 * i + 0], wg.x); awrite(wag[4 * i + 1], wg.y);
        awrite(wag[4 * i + 2], wg.z); awrite(wag[4 * i + 3], wg.w);
        awrite(wao[4 * i + 0], wo.x); awrite(wao[4 * i + 1], wo.y);
        awrite(wao[4 * i + 2], wo.z); awrite(wao[4 * i + 3], wo.w);
    }

    float c_reg = 0.0f;
    const float* xb = x + (size_t)b * NN * 3;

    for (int ch = 0; ch < NCH; ++ch) {
        const int base = ch * CH;
        __syncthreads();

        // ---- phase-0: conv+BN+ReLU -> hcT[c][n] ----
        {
            const int c  = t & 63;
            const int nb = t >> 6;           // 0..7, 4 timesteps each
            const float A0 = cf_s[0][c], A1 = cf_s[1][c];
            const float A2 = cf_s[2][c], D0 = cf_s[3][c];
            float4 hv;
            #pragma unroll
            for (int i = 0; i < 4; ++i) {
                const int n = nb * 4 + i;
                const float* xp = xb + (size_t)(base + n) * 3;
                float r = D0 + A0 * xp[0] + A1 * xp[1] + A2 * xp[2];
                ((float*)&hv)[i] = fmaxf(r, 0.0f);
            }
            *(float4*)&hcT[c][nb * 4] = hv;
        }
        __syncthreads();

        // ---- phase-1: xg[n][q][jj] = bias + W_ih[row]·hc[n]  (row = t) ----
        {
            const int q  = t >> 7;
            const int jj = t & 127;
            f32x2 acc2[16];
            const float bv = bias_s[t];
            #pragma unroll
            for (int n2 = 0; n2 < 16; ++n2) { acc2[n2].x = bv; acc2[n2].y = bv; }
            const float* wp = W_ih + (size_t)t * CMID;
            for (int k4 = 0; k4 < 16; ++k4) {
                float4 w4 = *(const float4*)(wp + 4 * k4);
                #pragma unroll
                for (int e = 0; e < 4; ++e) {
                    const int kk = 4 * k4 + e;
                    const float wv = ((const float*)&w4)[e];
                    f32x2 wd; wd.x = wv; wd.y = wv;
                    const float4* hr = (const float4*)&hcT[kk][0];
                    #pragma unroll
                    for (int n4 = 0; n4 < 8; ++n4) {
                        float4 hv = hr[n4];
                        f32x2 h01; h01.x = hv.x; h01.y = hv.y;
                        f32x2 h23; h23.x = hv.z; h23.y = hv.w;
                        pkfma(acc2[n4 * 2],     wd, h01);
                        pkfma(acc2[n4 * 2 + 1], wd, h23);
                    }
                }
            }
            #pragma unroll
            for (int n2 = 0; n2 < 16; ++n2) {
                xg_s[2 * n2][q][jj]     = acc2[n2].x;
                xg_s[2 * n2 + 1][q][jj] = acc2[n2].y;
            }
        }
        __syncthreads();

        // ---- phase-2: serial recurrence, one barrier per step ----
        #pragma unroll 1
        for (int k = 0; k < CH; ++k) {
            const int p = k & 1;            // CH even -> global parity = k&1
            // xg first (no h dependency -> issues early)
            float xq0 = xg_s[k][0][j];
            float xq1 = xg_s[k][1][j];
            float xq2 = xg_s[k][2][j];
            float xq3 = xg_s[k][3][j];

            f32x2 ai; ai.x = 0.f; ai.y = 0.f;
            f32x2 af = ai, ag = ai, ao = ai;
            const float4* hp4 = (const float4*)&h_p[p][s][0];
            #pragma unroll
            for (int i = 0; i < 8; ++i) {
                float4 hv = hp4[i];
                f32x2 hlo; hlo.x = hv.x; hlo.y = hv.y;
                f32x2 hhi; hhi.x = hv.z; hhi.y = hv.w;
                pkfma(ai, wif[0][2 * i],     hlo);
                pkfma(ai, wif[0][2 * i + 1], hhi);
                pkfma(af, wif[1][2 * i],     hlo);
                pkfma(af, wif[1][2 * i + 1], hhi);
                f32x2 g0; g0.x = aread(wag[4 * i + 0], k); g0.y = aread(wag[4 * i + 1], k);
                pkfma(ag, g0, hlo);
                f32x2 g1; g1.x = aread(wag[4 * i + 2], k); g1.y = aread(wag[4 * i + 3], k);
                pkfma(ag, g1, hhi);
                f32x2 o0; o0.x = aread(wao[4 * i + 0], k); o0.y = aread(wao[4 * i + 1], k);
                pkfma(ao, o0, hlo);
                f32x2 o1; o1.x = aread(wao[4 * i + 2], k); o1.y = aread(wao[4 * i + 3], k);
                pkfma(ao, o1, hhi);
            }
            float a0 = ai.x + ai.y;
            float a1 = af.x + af.y;
            float a2 = ag.x + ag.y;
            float a3 = ao.x + ao.y;

            // reduce across 4 slice-lanes (masks 1,2 -> DPP quad-perm)
            a0 += __shfl_xor(a0, 1); a0 += __shfl_xor(a0, 2);
            a1 += __shfl_xor(a1, 1); a1 += __shfl_xor(a1, 2);
            a2 += __shfl_xor(a2, 1); a2 += __shfl_xor(a2, 2);
            a3 += __shfl_xor(a3, 1); a3 += __shfl_xor(a3, 2);

            // xg (contains both biases) added once, after the reduce
            a0 += xq0; a1 += xq1; a2 += xq2; a3 += xq3;

            float gi = fsigmoid(a0);
            float gf = fsigmoid(a1);
            float gg = ftanh2(a2);
            float go = fsigmoid(a3);
            c_reg = gf * c_reg + gi * gg;     // identical in all 4 replicas
            float hv = go * ftanh2(c_reg);

            if (s == 0) h_p[p ^ 1][j >> 5][j & 31] = hv;
            __syncthreads();
        }
    }

    // ---- classifier head: final h in parity-0 buffer ----
    if (t < NCLS) {
        float acc = b_out[t];
        const float* wr = W_out + (size_t)t * HH;
        #pragma unroll
        for (int jj = 0; jj < HH; ++jj)
            acc = fmaf(wr[jj], h_p[0][jj >> 5][jj & 31], acc);
        out[(size_t)b * NCLS + t] = acc;
    }
}

extern "C" void kernel_launch(void* const* d_in, const int* in_sizes, int n_in,
                              void* d_out, int out_size, void* d_ws, size_t ws_size,
                              hipStream_t stream) {
    const float* x      = (const float*)d_in[0];
    const float* conv_w = (const float*)d_in[1];
    const float* conv_b = (const float*)d_in[2];
    const float* gamma  = (const float*)d_in[3];
    const float* beta   = (const float*)d_in[4];
    const float* rmean  = (const float*)d_in[5];
    const float* rvar   = (const float*)d_in[6];
    const float* W_ih   = (const float*)d_in[7];
    const float* W_hh   = (const float*)d_in[8];
    const float* b_ih   = (const float*)d_in[9];
    const float* b_hh   = (const float*)d_in[10];
    const float* W_out  = (const float*)d_in[11];
    const float* b_out  = (const float*)d_in[12];
    float* out = (float*)d_out;
    (void)d_ws; (void)ws_size; (void)in_sizes; (void)n_in; (void)out_size;

    lstm_seq_kernel<<<BB, 512, 0, stream>>>(x, conv_w, conv_b, gamma, beta,
                                            rmean, rvar, W_ih, W_hh, b_ih, b_hh,
                                            W_out, b_out, out);
}

// Round 11
// 2834.759 us; speedup vs baseline: 1.1926x; 1.1926x over previous
//
#include <hip/hip_runtime.h>
#include <math.h>

#define BB 128
#define NN 2048
#define CMID 64
#define HH 128
#define G4 512
#define NCLS 40
#define CH 32
#define NCH (NN / CH)
#define EPSV 1e-5f
#define HCP 36      // hcT row stride (pad): conflict-free b128 reads
#define XGP 129     // xg_s inner pad: store banks spread
#define HP 36       // h_p slice stride

typedef float f32x2 __attribute__((ext_vector_type(2)));

__device__ __forceinline__ float fsigmoid(float x) {
    return 1.0f / (1.0f + __expf(-x));
}
__device__ __forceinline__ float ftanh2(float x) {
    return 2.0f / (1.0f + __expf(-2.0f * x)) - 1.0f;
}
// AGPR park (R9/R10-proven mechanics).
__device__ __forceinline__ void awrite(float& a, float v) {
    asm volatile("v_accvgpr_write_b32 %0, %1" : "=a"(a) : "v"(v));
}
__device__ __forceinline__ float aread(const float& a, int dep) {
    float v;
    asm("v_accvgpr_read_b32 %0, %1" : "=v"(v) : "a"(a), "v"(dep));
    return v;
}
// Packed fp32 FMA: 2 MACs/instr (VOP3P).
__device__ __forceinline__ void pkfma(f32x2& d, f32x2 a, f32x2 b) {
    asm("v_pk_fma_f32 %0, %1, %2, %0" : "+v"(d) : "v"(a), "v"(b));
}

// 512 threads, 1 block/batch elem (1 block/CU at grid 128).
// Per 32-step chunk:
//   phase-0: conv+BN+ReLU -> hcT[c][n] (padded rows)
//   phase-1: xg = bias + W_ih*hc, thread = (row-quad, n-tile): 4 rows x 4 n,
//            2 passes. 4 FMAs per LDS float (vs 1 in R9/R10 -> killed the
//            LDS storm: 2 b128/step/thread instead of 16).
//   phase-2: serial recurrence, thread = (unit j=t>>2, slice s=t&3, 32 dims);
//            W_hh i,f in VGPRs (64), g,o in AGPRs (64, aread per use);
//            one barrier per step, xg (with biases) added after lane-reduce.
__global__ __attribute__((amdgpu_flat_work_group_size(512, 512),
                          amdgpu_waves_per_eu(2, 2)))
void lstm_seq_kernel(const float* __restrict__ x,
                     const float* __restrict__ conv_w, const float* __restrict__ conv_b,
                     const float* __restrict__ gamma,  const float* __restrict__ beta,
                     const float* __restrict__ rmean,  const float* __restrict__ rvar,
                     const float* __restrict__ W_ih,   const float* __restrict__ W_hh,
                     const float* __restrict__ b_ih,   const float* __restrict__ b_hh,
                     const float* __restrict__ W_out,  const float* __restrict__ b_out,
                     float* __restrict__ out)
{
    __shared__ float xg_s[CH][4][XGP];   // 66 KB gate pre-activations
    __shared__ float hcT[CMID][HCP];     // 9 KB  hc transposed, padded
    __shared__ float h_p[2][4][HP];      // hidden, slice-padded + dbuf
    __shared__ float cf_s[4][CMID];
    __shared__ float bias_s[G4];

    const int t = threadIdx.x;
    const int b = blockIdx.x;
    const int j = t >> 2;    // unit 0..127
    const int s = t & 3;     // h-slice 0..3 (32 dims)

    if (t < CMID) {
        float inv = gamma[t] * rsqrtf(rvar[t] + EPSV);
        cf_s[0][t] = conv_w[t * 3 + 0] * inv;
        cf_s[1][t] = conv_w[t * 3 + 1] * inv;
        cf_s[2][t] = conv_w[t * 3 + 2] * inv;
        cf_s[3][t] = (conv_b[t] - rmean[t]) * inv + beta[t];
    }
    bias_s[t] = b_ih[t] + b_hh[t];
    if (t < 2 * 4 * HP) ((float*)h_p)[t] = 0.0f;

    // ---- W_hh residency: i,f -> VGPR pairs; g,o -> AGPRs ----
    f32x2 wif[2][16];
    #pragma unroll
    for (int q = 0; q < 2; ++q) {
        const float* p = W_hh + (size_t)(q * HH + j) * HH + s * 32;
        #pragma unroll
        for (int i = 0; i < 8; ++i) {
            float4 w4 = *(const float4*)(p + 4 * i);
            wif[q][2 * i].x     = w4.x; wif[q][2 * i].y     = w4.y;
            wif[q][2 * i + 1].x = w4.z; wif[q][2 * i + 1].y = w4.w;
        }
    }
    float wag[32], wao[32];
    #pragma unroll
    for (int i = 0; i < 8; ++i) {
        float4 wg = *(const float4*)(W_hh + (size_t)(2 * HH + j) * HH + s * 32 + 4 * i);
        float4 wo = *(const float4*)(W_hh + (size_t)(3 * HH + j) * HH + s * 32 + 4 * i);
        awrite(wag[4 * i + 0], wg.x); awrite(wag[4 * i + 1], wg.y);
        awrite(wag[4 * i + 2], wg.z); awrite(wag[4 * i + 3], wg.w);
        awrite(wao[4 * i + 0], wo.x); awrite(wao[4 * i + 1], wo.y);
        awrite(wao[4 * i + 2], wo.z); awrite(wao[4 * i + 3], wo.w);
    }

    float c_reg = 0.0f;
    const float* xb = x + (size_t)b * NN * 3;

    for (int ch = 0; ch < NCH; ++ch) {
        const int base = ch * CH;
        __syncthreads();   // prior chunk's xg fully consumed; init visible

        // ---- phase-0: conv+BN+ReLU -> hcT ----
        {
            const int c  = t & 63;
            const int nb = t >> 6;           // 0..7, 4 timesteps each
            const float A0 = cf_s[0][c], A1 = cf_s[1][c];
            const float A2 = cf_s[2][c], D0 = cf_s[3][c];
            float4 hv;
            #pragma unroll
            for (int i = 0; i < 4; ++i) {
                const int n = nb * 4 + i;
                const float* xp = xb + (size_t)(base + n) * 3;
                float r = D0 + A0 * xp[0] + A1 * xp[1] + A2 * xp[2];
                ((float*)&hv)[i] = fmaxf(r, 0.0f);
            }
            *(float4*)&hcT[c][nb * 4] = hv;
        }
        __syncthreads();

        // ---- phase-1: xg = bias + W_ih*hc ; thread = 4 rows x 4 timesteps ----
        #pragma unroll
        for (int pass = 0; pass < 2; ++pass) {
            const int rq   = t >> 3;               // 0..63
            const int nt   = t & 7;                // n-tile: n = nt*4..+3
            const int row0 = pass * 256 + rq * 4;
            f32x2 acc[4][2];
            #pragma unroll
            for (int u = 0; u < 4; ++u) {
                const float bv = bias_s[row0 + u];
                acc[u][0].x = bv; acc[u][0].y = bv;
                acc[u][1].x = bv; acc[u][1].y = bv;
            }
            const float* wp = W_ih + (size_t)row0 * CMID;
            for (int k4 = 0; k4 < 16; ++k4) {
                float4 w[4];
                #pragma unroll
                for (int u = 0; u < 4; ++u)
                    w[u] = *(const float4*)(wp + u * CMID + k4 * 4);
                #pragma unroll
                for (int e = 0; e < 4; ++e) {
                    const int kk = k4 * 4 + e;
                    float4 hcv = *(const float4*)&hcT[kk][nt * 4];
                    f32x2 hlo; hlo.x = hcv.x; hlo.y = hcv.y;
                    f32x2 hhi; hhi.x = hcv.z; hhi.y = hcv.w;
                    #pragma unroll
                    for (int u = 0; u < 4; ++u) {
                        const float wv = ((const float*)&w[u])[e];
                        f32x2 wd; wd.x = wv; wd.y = wv;
                        pkfma(acc[u][0], wd, hlo);
                        pkfma(acc[u][1], wd, hhi);
                    }
                }
            }
            #pragma unroll
            for (int u = 0; u < 4; ++u) {
                const int row = row0 + u;
                const int q   = row >> 7;
                const int jj  = row & 127;
                xg_s[nt * 4 + 0][q][jj] = acc[u][0].x;
                xg_s[nt * 4 + 1][q][jj] = acc[u][0].y;
                xg_s[nt * 4 + 2][q][jj] = acc[u][1].x;
                xg_s[nt * 4 + 3][q][jj] = acc[u][1].y;
            }
        }
        __syncthreads();

        // ---- phase-2: serial recurrence, one barrier per step ----
        for (int k = 0; k < CH; ++k) {
            const int p = k & 1;            // base even -> global parity = k&1
            float xq0 = xg_s[k][0][j];
            float xq1 = xg_s[k][1][j];
            float xq2 = xg_s[k][2][j];
            float xq3 = xg_s[k][3][j];

            f32x2 ai; ai.x = 0.f; ai.y = 0.f;
            f32x2 af = ai, ag = ai, ao = ai;
            const float4* hp4 = (const float4*)&h_p[p][s][0];
            #pragma unroll
            for (int i = 0; i < 8; ++i) {
                float4 hv = hp4[i];
                f32x2 hlo; hlo.x = hv.x; hlo.y = hv.y;
                f32x2 hhi; hhi.x = hv.z; hhi.y = hv.w;
                pkfma(ai, wif[0][2 * i],     hlo);
                pkfma(ai, wif[0][2 * i + 1], hhi);
                pkfma(af, wif[1][2 * i],     hlo);
                pkfma(af, wif[1][2 * i + 1], hhi);
                f32x2 g0; g0.x = aread(wag[4 * i + 0], k); g0.y = aread(wag[4 * i + 1], k);
                pkfma(ag, g0, hlo);
                f32x2 g1; g1.x = aread(wag[4 * i + 2], k); g1.y = aread(wag[4 * i + 3], k);
                pkfma(ag, g1, hhi);
                f32x2 o0; o0.x = aread(wao[4 * i + 0], k); o0.y = aread(wao[4 * i + 1], k);
                pkfma(ao, o0, hlo);
                f32x2 o1; o1.x = aread(wao[4 * i + 2], k); o1.y = aread(wao[4 * i + 3], k);
                pkfma(ao, o1, hhi);
            }
            float a0 = ai.x + ai.y;
            float a1 = af.x + af.y;
            float a2 = ag.x + ag.y;
            float a3 = ao.x + ao.y;

            a0 += __shfl_xor(a0, 1); a0 += __shfl_xor(a0, 2);
            a1 += __shfl_xor(a1, 1); a1 += __shfl_xor(a1, 2);
            a2 += __shfl_xor(a2, 1); a2 += __shfl_xor(a2, 2);
            a3 += __shfl_xor(a3, 1); a3 += __shfl_xor(a3, 2);

            a0 += xq0; a1 += xq1; a2 += xq2; a3 += xq3;

            float gi = fsigmoid(a0);
            float gf = fsigmoid(a1);
            float gg = ftanh2(a2);
            float go = fsigmoid(a3);
            c_reg = gf * c_reg + gi * gg;     // identical in all 4 replicas
            float hv = go * ftanh2(c_reg);

            if (s == 0) h_p[p ^ 1][j >> 5][j & 31] = hv;
            __syncthreads();
        }
    }

    // ---- classifier head: final h in parity-0 buffer ----
    if (t < NCLS) {
        float acc = b_out[t];
        const float* wr = W_out + (size_t)t * HH;
        #pragma unroll
        for (int jj = 0; jj < HH; ++jj)
            acc = fmaf(wr[jj], h_p[0][jj >> 5][jj & 31], acc);
        out[(size_t)b * NCLS + t] = acc;
    }
}

extern "C" void kernel_launch(void* const* d_in, const int* in_sizes, int n_in,
                              void* d_out, int out_size, void* d_ws, size_t ws_size,
                              hipStream_t stream) {
    const float* x      = (const float*)d_in[0];
    const float* conv_w = (const float*)d_in[1];
    const float* conv_b = (const float*)d_in[2];
    const float* gamma  = (const float*)d_in[3];
    const float* beta   = (const float*)d_in[4];
    const float* rmean  = (const float*)d_in[5];
    const float* rvar   = (const float*)d_in[6];
    const float* W_ih   = (const float*)d_in[7];
    const float* W_hh   = (const float*)d_in[8];
    const float* b_ih   = (const float*)d_in[9];
    const float* b_hh   = (const float*)d_in[10];
    const float* W_out  = (const float*)d_in[11];
    const float* b_out  = (const float*)d_in[12];
    float* out = (float*)d_out;
    (void)d_ws; (void)ws_size; (void)in_sizes; (void)n_in; (void)out_size;

    lstm_seq_kernel<<<BB, 512, 0, stream>>>(x, conv_w, conv_b, gamma, beta,
                                            rmean, rvar, W_ih, W_hh, b_ih, b_hh,
                                            W_out, b_out, out);
}

// Round 13
// 2225.247 us; speedup vs baseline: 1.5192x; 1.2739x over previous
//
#include <hip/hip_runtime.h>
#include <math.h>

#define BB 128
#define NN 2048
#define CMID 64
#define HH 128
#define G4 512
#define NCLS 40
#define CH 32
#define NCH (NN / CH)
#define EPSV 1e-5f
#define HCP 36      // hcT row stride (pad)
#define XGP 129     // xg_s inner pad
#define HP 36       // h_p slice stride
#define LOG2E 1.44269504088896340736f

typedef float f32x2 __attribute__((ext_vector_type(2)));

// fast activation primitives: single-instruction exp2 / rcp (VALU trans pipe)
__device__ __forceinline__ float fexp2(float x) {
#if __has_builtin(__builtin_amdgcn_exp2f)
    return __builtin_amdgcn_exp2f(x);
#else
    return __expf(x * 0.69314718056f);
#endif
}
__device__ __forceinline__ float frcp(float x) {
#if __has_builtin(__builtin_amdgcn_rcpf)
    return __builtin_amdgcn_rcpf(x);
#else
    return 1.0f / x;
#endif
}
__device__ __forceinline__ float fsigmoid(float x) {          // 4 instr
    return frcp(1.0f + fexp2(x * -LOG2E));
}
__device__ __forceinline__ float ftanh2(float x) {            // 5 instr
    return fmaf(2.0f, frcp(1.0f + fexp2(x * (-2.0f * LOG2E))), -1.0f);
}
// DPP quad-perm reduce (masks 1,2) -- guaranteed VALU, never LDS pipe.
// dpp_ctrl must be an integer CONSTANT -> template parameter (R12 fix).
template <int CODE>
__device__ __forceinline__ float qperm(float x) {
    return __int_as_float(__builtin_amdgcn_update_dpp(
        0, __float_as_int(x), CODE, 0xF, 0xF, true));
}
__device__ __forceinline__ float qreduce(float x) {
    x += qperm<0xB1>(x);   // quad_perm [1,0,3,2]  == xor 1
    x += qperm<0x4E>(x);   // quad_perm [2,3,0,1]  == xor 2
    return x;
}
// AGPR park (R9-R11 proven). aread carries loop-variant dep -> in-loop
// scheduling freedom, no hoisting.
__device__ __forceinline__ void awrite(float& a, float v) {
    asm volatile("v_accvgpr_write_b32 %0, %1" : "=a"(a) : "v"(v));
}
__device__ __forceinline__ float aread(const float& a, int dep) {
    float v;
    asm("v_accvgpr_read_b32 %0, %1" : "=v"(v) : "a"(a), "v"(dep));
    return v;
}
__device__ __forceinline__ void pkfma(f32x2& d, f32x2 a, f32x2 b) {
    asm("v_pk_fma_f32 %0, %1, %2, %0" : "+v"(d) : "v"(a), "v"(b));
}

// 512 threads, 1 block/batch elem.  Phase-0/1 identical to R11 (verified).
// Phase-2 weight residency (128 fl/thread needed, 128-VGPR hard cap):
//   gate i,f: 64 fl VGPR (pkfma); gate g: 16 fl VGPR + 16 fl AGPR;
//   gate o: 32 fl AGPR (scalar fmaf fed by accvgpr_read).
// Serial tail: exp2/rcp builtins + DPP reduce (no div sequence, no LDS shfl).
__global__ __attribute__((amdgpu_flat_work_group_size(512, 512),
                          amdgpu_waves_per_eu(2, 2)))
void lstm_seq_kernel(const float* __restrict__ x,
                     const float* __restrict__ conv_w, const float* __restrict__ conv_b,
                     const float* __restrict__ gamma,  const float* __restrict__ beta,
                     const float* __restrict__ rmean,  const float* __restrict__ rvar,
                     const float* __restrict__ W_ih,   const float* __restrict__ W_hh,
                     const float* __restrict__ b_ih,   const float* __restrict__ b_hh,
                     const float* __restrict__ W_out,  const float* __restrict__ b_out,
                     float* __restrict__ out)
{
    __shared__ float xg_s[CH][4][XGP];   // 66 KB gate pre-activations
    __shared__ float hcT[CMID][HCP];     // 9 KB  hc transposed, padded
    __shared__ float h_p[2][4][HP];      // hidden, slice-padded + dbuf
    __shared__ float cf_s[4][CMID];
    __shared__ float bias_s[G4];

    const int t = threadIdx.x;
    const int b = blockIdx.x;
    const int j = t >> 2;    // unit 0..127
    const int s = t & 3;     // h-slice 0..3 (32 dims)

    if (t < CMID) {
        float inv = gamma[t] * rsqrtf(rvar[t] + EPSV);
        cf_s[0][t] = conv_w[t * 3 + 0] * inv;
        cf_s[1][t] = conv_w[t * 3 + 1] * inv;
        cf_s[2][t] = conv_w[t * 3 + 2] * inv;
        cf_s[3][t] = (conv_b[t] - rmean[t]) * inv + beta[t];
    }
    bias_s[t] = b_ih[t] + b_hh[t];
    if (t < 2 * 4 * HP) ((float*)h_p)[t] = 0.0f;

    // ---- W_hh residency ----
    f32x2 wif[2][16];            // gates i,f : 64 VGPR
    #pragma unroll
    for (int q = 0; q < 2; ++q) {
        const float* p = W_hh + (size_t)(q * HH + j) * HH + s * 32;
        #pragma unroll
        for (int i = 0; i < 8; ++i) {
            float4 w4 = *(const float4*)(p + 4 * i);
            wif[q][2 * i].x     = w4.x; wif[q][2 * i].y     = w4.y;
            wif[q][2 * i + 1].x = w4.z; wif[q][2 * i + 1].y = w4.w;
        }
    }
    f32x2 wgv[8];                // gate g dims 0..15 : 16 VGPR
    #pragma unroll
    for (int i = 0; i < 4; ++i) {
        float4 w4 = *(const float4*)(W_hh + (size_t)(2 * HH + j) * HH + s * 32 + 4 * i);
        wgv[2 * i].x     = w4.x; wgv[2 * i].y     = w4.y;
        wgv[2 * i + 1].x = w4.z; wgv[2 * i + 1].y = w4.w;
    }
    float wga[16];               // gate g dims 16..31 : AGPR
    #pragma unroll
    for (int i = 0; i < 4; ++i) {
        float4 w4 = *(const float4*)(W_hh + (size_t)(2 * HH + j) * HH + s * 32 + 16 + 4 * i);
        awrite(wga[4 * i + 0], w4.x); awrite(wga[4 * i + 1], w4.y);
        awrite(wga[4 * i + 2], w4.z); awrite(wga[4 * i + 3], w4.w);
    }
    float woa[32];               // gate o : AGPR
    #pragma unroll
    for (int i = 0; i < 8; ++i) {
        float4 w4 = *(const float4*)(W_hh + (size_t)(3 * HH + j) * HH + s * 32 + 4 * i);
        awrite(woa[4 * i + 0], w4.x); awrite(woa[4 * i + 1], w4.y);
        awrite(woa[4 * i + 2], w4.z); awrite(woa[4 * i + 3], w4.w);
    }

    float c_reg = 0.0f;
    const float* xb = x + (size_t)b * NN * 3;

    for (int ch = 0; ch < NCH; ++ch) {
        const int base = ch * CH;
        __syncthreads();

        // ---- phase-0: conv+BN+ReLU -> hcT (R11 verbatim) ----
        {
            const int c  = t & 63;
            const int nb = t >> 6;
            const float A0 = cf_s[0][c], A1 = cf_s[1][c];
            const float A2 = cf_s[2][c], D0 = cf_s[3][c];
            float4 hv;
            #pragma unroll
            for (int i = 0; i < 4; ++i) {
                const int n = nb * 4 + i;
                const float* xp = xb + (size_t)(base + n) * 3;
                float r = D0 + A0 * xp[0] + A1 * xp[1] + A2 * xp[2];
                ((float*)&hv)[i] = fmaxf(r, 0.0f);
            }
            *(float4*)&hcT[c][nb * 4] = hv;
        }
        __syncthreads();

        // ---- phase-1: xg = bias + W_ih*hc (R11 verbatim) ----
        #pragma unroll
        for (int pass = 0; pass < 2; ++pass) {
            const int rq   = t >> 3;
            const int nt   = t & 7;
            const int row0 = pass * 256 + rq * 4;
            f32x2 acc[4][2];
            #pragma unroll
            for (int u = 0; u < 4; ++u) {
                const float bv = bias_s[row0 + u];
                acc[u][0].x = bv; acc[u][0].y = bv;
                acc[u][1].x = bv; acc[u][1].y = bv;
            }
            const float* wp = W_ih + (size_t)row0 * CMID;
            for (int k4 = 0; k4 < 16; ++k4) {
                float4 w[4];
                #pragma unroll
                for (int u = 0; u < 4; ++u)
                    w[u] = *(const float4*)(wp + u * CMID + k4 * 4);
                #pragma unroll
                for (int e = 0; e < 4; ++e) {
                    const int kk = k4 * 4 + e;
                    float4 hcv = *(const float4*)&hcT[kk][nt * 4];
                    f32x2 hlo; hlo.x = hcv.x; hlo.y = hcv.y;
                    f32x2 hhi; hhi.x = hcv.z; hhi.y = hcv.w;
                    #pragma unroll
                    for (int u = 0; u < 4; ++u) {
                        const float wv = ((const float*)&w[u])[e];
                        f32x2 wd; wd.x = wv; wd.y = wv;
                        pkfma(acc[u][0], wd, hlo);
                        pkfma(acc[u][1], wd, hhi);
                    }
                }
            }
            #pragma unroll
            for (int u = 0; u < 4; ++u) {
                const int row = row0 + u;
                const int q   = row >> 7;
                const int jj  = row & 127;
                xg_s[nt * 4 + 0][q][jj] = acc[u][0].x;
                xg_s[nt * 4 + 1][q][jj] = acc[u][0].y;
                xg_s[nt * 4 + 2][q][jj] = acc[u][1].x;
                xg_s[nt * 4 + 3][q][jj] = acc[u][1].y;
            }
        }
        __syncthreads();

        // ---- phase-2: serial recurrence, one barrier per step ----
        for (int k = 0; k < CH; ++k) {
            const int p = k & 1;
            // xg early: latency overlaps the h-read + FMA block
            float xq0 = xg_s[k][0][j];
            float xq1 = xg_s[k][1][j];
            float xq2 = xg_s[k][2][j];
            float xq3 = xg_s[k][3][j];

            f32x2 ai; ai.x = 0.f; ai.y = 0.f;
            f32x2 af = ai, agv = ai;
            float ag = 0.f, ao = 0.f;
            const float4* hp4 = (const float4*)&h_p[p][s][0];
            #pragma unroll
            for (int i = 0; i < 8; ++i) {
                float4 hv = hp4[i];
                f32x2 hlo; hlo.x = hv.x; hlo.y = hv.y;
                f32x2 hhi; hhi.x = hv.z; hhi.y = hv.w;
                pkfma(ai, wif[0][2 * i],     hlo);
                pkfma(ai, wif[0][2 * i + 1], hhi);
                pkfma(af, wif[1][2 * i],     hlo);
                pkfma(af, wif[1][2 * i + 1], hhi);
                if (i < 4) {                       // g dims 0..15: VGPR pkfma
                    pkfma(agv, wgv[2 * i],     hlo);
                    pkfma(agv, wgv[2 * i + 1], hhi);
                } else {                           // g dims 16..31: AGPR scalar
                    const int ib = (i - 4) * 4;
                    ag = fmaf(aread(wga[ib + 0], k), hv.x, ag);
                    ag = fmaf(aread(wga[ib + 1], k), hv.y, ag);
                    ag = fmaf(aread(wga[ib + 2], k), hv.z, ag);
                    ag = fmaf(aread(wga[ib + 3], k), hv.w, ag);
                }
                ao = fmaf(aread(woa[4 * i + 0], k), hv.x, ao);
                ao = fmaf(aread(woa[4 * i + 1], k), hv.y, ao);
                ao = fmaf(aread(woa[4 * i + 2], k), hv.z, ao);
                ao = fmaf(aread(woa[4 * i + 3], k), hv.w, ao);
            }
            float a0 = ai.x + ai.y;
            float a1 = af.x + af.y;
            float a2 = agv.x + agv.y + ag;
            float a3 = ao;

            a0 = qreduce(a0);
            a1 = qreduce(a1);
            a2 = qreduce(a2);
            a3 = qreduce(a3);

            a0 += xq0; a1 += xq1; a2 += xq2; a3 += xq3;

            float gi = fsigmoid(a0);
            float gf = fsigmoid(a1);
            float gg = ftanh2(a2);
            float go = fsigmoid(a3);
            c_reg = fmaf(gf, c_reg, gi * gg);   // identical in all 4 replicas
            float hv = go * ftanh2(c_reg);

            if (s == 0) h_p[p ^ 1][j >> 5][j & 31] = hv;
            __syncthreads();
        }
    }

    // ---- classifier head: final h in parity-0 buffer ----
    if (t < NCLS) {
        float acc = b_out[t];
        const float* wr = W_out + (size_t)t * HH;
        #pragma unroll
        for (int jj = 0; jj < HH; ++jj)
            acc = fmaf(wr[jj], h_p[0][jj >> 5][jj & 31], acc);
        out[(size_t)b * NCLS + t] = acc;
    }
}

extern "C" void kernel_launch(void* const* d_in, const int* in_sizes, int n_in,
                              void* d_out, int out_size, void* d_ws, size_t ws_size,
                              hipStream_t stream) {
    const float* x      = (const float*)d_in[0];
    const float* conv_w = (const float*)d_in[1];
    const float* conv_b = (const float*)d_in[2];
    const float* gamma  = (const float*)d_in[3];
    const float* beta   = (const float*)d_in[4];
    const float* rmean  = (const float*)d_in[5];
    const float* rvar   = (const float*)d_in[6];
    const float* W_ih   = (const float*)d_in[7];
    const float* W_hh   = (const float*)d_in[8];
    const float* b_ih   = (const float*)d_in[9];
    const float* b_hh   = (const float*)d_in[10];
    const float* W_out  = (const float*)d_in[11];
    const float* b_out  = (const float*)d_in[12];
    float* out = (float*)d_out;
    (void)d_ws; (void)ws_size; (void)in_sizes; (void)n_in; (void)out_size;

    lstm_seq_kernel<<<BB, 512, 0, stream>>>(x, conv_w, conv_b, gamma, beta,
                                            rmean, rvar, W_ih, W_hh, b_ih, b_hh,
                                            W_out, b_out, out);
}